// Round 9
// baseline (211.151 us; speedup 1.0000x reference)
//
#include <hip/hip_runtime.h>

// SoftFAPELoss: B=8, N=M=4096, D=3. Exact two-pass shifted softmax,
// packed-FP32 hot loop, 8 rows/lane, occupancy-tuned.
// softfape_main: grid 1024 x 512 thr (8 waves) = 4 blocks/CU. Block =
//   (b, 512-row group, 1/16th of M = 256 q). q's transformed+prescaled into
//   4 KB LDS (q.xyz = -2c*y, q.w = c*|y|^2); wave scans a 32-q slice via
//   wave-uniform ds_read_b128 broadcast; lane owns 8 rows as 4 float2 packs.
//   Pass 1: A = q.p + c|q|^2 (3 pk_fma), minA = pk_min. Block merge across
//     8 waves -> uniform per-row shift sh (A-units).
//   Pass 2: arg = sh - A <= 0 (pk), w = exp2(arg), L += w, SA += w*arg.
//     Chunk-min term -> w = 1 exactly, so L >= 1: no underflow possible.
//   LDS diet: ONE 16 KB partial buffer reused (minima -> L -> SA) with
//   barriers between phases; 24.5 KB total -> LDS never the occupancy cap.
// softfape_finalize: merge 16 chunk partials per row (exp2(m - m_i) <= 1),
//   wd = m - SA/L, block-reduce, atomicAdd * T*ln2/(B*N).

#define B_    8
#define N_    4096
#define M_    4096
#define NWAVE 8
#define BLOCK (NWAVE * 64)        // 512
#define ROWS  512                 // rows per block (8 per lane)
#define MSPL  16                  // M split across blocks
#define QCH   (M_ / MSPL)         // 256 q per block
#define WQ    (QCH / NWAVE)       // 32 q per wave
#define LOG2E 1.4426950408889634f
#define LN2   0.6931471805599453f
#define BIGF  3.0e38f

typedef float v2f __attribute__((ext_vector_type(2)));

__global__ __launch_bounds__(BLOCK, 8) void softfape_main(
    const float* __restrict__ X_pred, const float* __restrict__ X_true,
    const float* __restrict__ R_pred, const float* __restrict__ t_pred,
    const float* __restrict__ R_true, const float* __restrict__ t_true,
    const float* __restrict__ temp,
    float4* __restrict__ Pg)
{
    __shared__ float4 Q[QCH];            // 4 KB
    __shared__ float  Wp[NWAVE][ROWS];   // 16 KB, reused: minima -> L -> SA
    __shared__ float  shl[ROWS];         // 2 KB (uniform shift per row, A-units)
    __shared__ float  pwl[ROWS];         // 2 KB (c*|p|^2 per row)

    const int tid  = threadIdx.x;
    const int wave = tid >> 6;
    const int lane = tid & 63;
    const int x    = blockIdx.x;
    const int ms   = x & 15;
    const int rg   = (x >> 4) & 7;       // 8 row-groups of 512 rows
    const int b    = x >> 7;

    const float T   = temp[0];
    const float c   = LOG2E / T;
    const float m2c = -2.0f * c;

    // ---- stage 256 transformed+prescaled q's (threads 0..127, 2 each) ----
    if (tid < QCH / 2) {
        const float g00 = R_true[b*9+0], g01 = R_true[b*9+1], g02 = R_true[b*9+2];
        const float g10 = R_true[b*9+3], g11 = R_true[b*9+4], g12 = R_true[b*9+5];
        const float g20 = R_true[b*9+6], g21 = R_true[b*9+7], g22 = R_true[b*9+8];
        const float u0  = t_true[b*3+0], u1 = t_true[b*3+1], u2 = t_true[b*3+2];
        const float2* xt = (const float2*)(X_true + ((size_t)b * M_ + ms * QCH) * 3);
        const float2 f0 = xt[3*tid+0], f1 = xt[3*tid+1], f2 = xt[3*tid+2];
        {
            const float y0 = fmaf(g00, f0.x, fmaf(g01, f0.y, fmaf(g02, f1.x, u0)));
            const float y1 = fmaf(g10, f0.x, fmaf(g11, f0.y, fmaf(g12, f1.x, u1)));
            const float y2 = fmaf(g20, f0.x, fmaf(g21, f0.y, fmaf(g22, f1.x, u2)));
            const float nn = fmaf(y0, y0, fmaf(y1, y1, y2 * y2));
            Q[2*tid]   = make_float4(m2c*y0, m2c*y1, m2c*y2, c*nn);
        }
        {
            const float y0 = fmaf(g00, f1.y, fmaf(g01, f2.x, fmaf(g02, f2.y, u0)));
            const float y1 = fmaf(g10, f1.y, fmaf(g11, f2.x, fmaf(g12, f2.y, u1)));
            const float y2 = fmaf(g20, f1.y, fmaf(g21, f2.x, fmaf(g22, f2.y, u2)));
            const float nn = fmaf(y0, y0, fmaf(y1, y1, y2 * y2));
            Q[2*tid+1] = make_float4(m2c*y0, m2c*y1, m2c*y2, c*nn);
        }
    }

    // ---- my 8 rows: transform, pack into float2 pairs ----
    v2f px2[4], py2[4], pz2[4];
    {
        const float h00 = R_pred[b*9+0], h01 = R_pred[b*9+1], h02 = R_pred[b*9+2];
        const float h10 = R_pred[b*9+3], h11 = R_pred[b*9+4], h12 = R_pred[b*9+5];
        const float h20 = R_pred[b*9+6], h21 = R_pred[b*9+7], h22 = R_pred[b*9+8];
        const float v0 = t_pred[b*3+0], v1 = t_pred[b*3+1], v2 = t_pred[b*3+2];
        const float4* xp = (const float4*)(X_pred + ((size_t)b * N_ + rg * ROWS + lane * 8) * 3);
        const float4 a0 = xp[0], a1 = xp[1], a2 = xp[2];
        const float4 a3 = xp[3], a4 = xp[4], a5 = xp[5];
        const float rx[8] = {a0.x, a0.w, a1.z, a2.y, a3.x, a3.w, a4.z, a5.y};
        const float ry[8] = {a0.y, a1.x, a1.w, a2.z, a3.y, a4.x, a4.w, a5.z};
        const float rz[8] = {a0.z, a1.y, a2.x, a2.w, a3.z, a4.y, a5.x, a5.w};
        #pragma unroll
        for (int j = 0; j < 8; ++j) {
            const float ppx = fmaf(h00, rx[j], fmaf(h01, ry[j], fmaf(h02, rz[j], v0)));
            const float ppy = fmaf(h10, rx[j], fmaf(h11, ry[j], fmaf(h12, rz[j], v1)));
            const float ppz = fmaf(h20, rx[j], fmaf(h21, ry[j], fmaf(h22, rz[j], v2)));
            px2[j >> 1][j & 1] = ppx;
            py2[j >> 1][j & 1] = ppy;
            pz2[j >> 1][j & 1] = ppz;
            if (wave == 0) pwl[8*lane + j] = c * fmaf(ppx, ppx, fmaf(ppy, ppy, ppz * ppz));
        }
    }

    __syncthreads();   // #1: Q, pwl staged

    const float4* __restrict__ Qw = Q + wave * WQ;

    // ---- pass 1: packed min of A over my 32-q slice ----
    v2f mA2[4] = {{BIGF, BIGF}, {BIGF, BIGF}, {BIGF, BIGF}, {BIGF, BIGF}};
    #pragma unroll 4
    for (int k = 0; k < WQ; ++k) {
        const float4 q = Qw[k];   // ds_read_b128, wave-uniform broadcast
        const v2f qx = {q.x, q.x}, qy = {q.y, q.y}, qz = {q.z, q.z}, qw = {q.w, q.w};
        #pragma unroll
        for (int j = 0; j < 4; ++j) {
            const v2f A = qx * px2[j] + (qy * py2[j] + (qz * pz2[j] + qw));
            mA2[j] = __builtin_elementwise_min(mA2[j], A);
        }
    }
    #pragma unroll
    for (int j = 0; j < 4; ++j) {
        Wp[wave][8*lane + 2*j]     = mA2[j].x;
        Wp[wave][8*lane + 2*j + 1] = mA2[j].y;
    }
    __syncthreads();   // #2: minima written

    // ---- block-uniform per-row shift (A-units) ----
    {
        float m = Wp[0][tid];
        #pragma unroll
        for (int w2 = 1; w2 < NWAVE; ++w2) m = fminf(m, Wp[w2][tid]);
        shl[tid] = m;
    }
    __syncthreads();   // #3: shl ready, all Wp reads done

    v2f sh2[4];
    {
        const float4 s0 = *(const float4*)&shl[8*lane];
        const float4 s1 = *(const float4*)&shl[8*lane + 4];
        sh2[0] = (v2f){s0.x, s0.y};  sh2[1] = (v2f){s0.z, s0.w};
        sh2[2] = (v2f){s1.x, s1.y};  sh2[3] = (v2f){s1.z, s1.w};
    }

    // ---- pass 2: packed shifted sums ----
    v2f L2[4]  = {{0.f,0.f},{0.f,0.f},{0.f,0.f},{0.f,0.f}};
    v2f SA2[4] = {{0.f,0.f},{0.f,0.f},{0.f,0.f},{0.f,0.f}};
    #pragma unroll 4
    for (int k = 0; k < WQ; ++k) {
        const float4 q = Qw[k];
        const v2f qx = {q.x, q.x}, qy = {q.y, q.y}, qz = {q.z, q.z}, qw = {q.w, q.w};
        #pragma unroll
        for (int j = 0; j < 4; ++j) {
            const v2f A   = qx * px2[j] + (qy * py2[j] + (qz * pz2[j] + qw));
            const v2f arg = sh2[j] - A;                       // <= 0
            const v2f w   = {__builtin_amdgcn_exp2f(arg.x),
                             __builtin_amdgcn_exp2f(arg.y)};  // chunk-min -> 1
            L2[j]  += w;
            SA2[j]  = w * arg + SA2[j];                       // Sum w*(m_d - d)
        }
    }

    // ---- merge L (reuse Wp), then SA (reuse Wp again) ----
    #pragma unroll
    for (int j = 0; j < 4; ++j) {
        Wp[wave][8*lane + 2*j]     = L2[j].x;
        Wp[wave][8*lane + 2*j + 1] = L2[j].y;
    }
    __syncthreads();   // #4: L partials written
    float Lr = 0.0f;
    #pragma unroll
    for (int w2 = 0; w2 < NWAVE; ++w2) Lr += Wp[w2][tid];
    __syncthreads();   // #5: L reads done
    #pragma unroll
    for (int j = 0; j < 4; ++j) {
        Wp[wave][8*lane + 2*j]     = SA2[j].x;
        Wp[wave][8*lane + 2*j + 1] = SA2[j].y;
    }
    __syncthreads();   // #6: SA partials written
    float Sr = 0.0f;
    #pragma unroll
    for (int w2 = 0; w2 < NWAVE; ++w2) Sr += Wp[w2][tid];

    // ---- chunk partial out (chunk-major, lane-coalesced) ----
    {
        const size_t row = (size_t)b * N_ + rg * ROWS + tid;
        // m_d = minA + pw (d-units); L = sum exp2(m_d - d); SA = sum w*(m_d - d)
        Pg[(size_t)ms * (B_ * N_) + row] = make_float4(shl[tid] + pwl[tid], Lr, Sr, 0.0f);
    }
}

__global__ __launch_bounds__(256) void softfape_finalize(
    const float4* __restrict__ Pg, const float* __restrict__ temp,
    float* __restrict__ out)
{
    __shared__ float ws4[4];
    const int tid = threadIdx.x;
    const size_t row = (size_t)blockIdx.x * 256 + tid;

    float4 P[MSPL];
    #pragma unroll
    for (int i = 0; i < MSPL; ++i) P[i] = Pg[(size_t)i * (B_ * N_) + row];

    float m = P[0].x;
    #pragma unroll
    for (int i = 1; i < MSPL; ++i) m = fminf(m, P[i].x);

    float L = 0.0f, SA = 0.0f;
    #pragma unroll
    for (int i = 0; i < MSPL; ++i) {
        const float dm = m - P[i].x;                    // <= 0
        const float f  = __builtin_amdgcn_exp2f(dm);    // global-min chunk -> 1
        L  = fmaf(P[i].y, f, L);
        SA = fmaf(f, fmaf(dm, P[i].y, P[i].z), SA);
    }
    float wd = m - SA / L;   // = c * weighted_distance(row); L >= 1 guaranteed

    wd += __shfl_xor(wd, 1);  wd += __shfl_xor(wd, 2);  wd += __shfl_xor(wd, 4);
    wd += __shfl_xor(wd, 8);  wd += __shfl_xor(wd, 16); wd += __shfl_xor(wd, 32);
    if ((tid & 63) == 0) ws4[tid >> 6] = wd;
    __syncthreads();
    if (tid == 0) {
        const float s = ws4[0] + ws4[1] + ws4[2] + ws4[3];
        const float scale = temp[0] * LN2 / ((float)B_ * (float)N_);  // 1/c, mean
        atomicAdd(out, s * scale);
    }
}

extern "C" void kernel_launch(void* const* d_in, const int* in_sizes, int n_in,
                              void* d_out, int out_size, void* d_ws, size_t ws_size,
                              hipStream_t stream) {
    const float* X_pred = (const float*)d_in[0];
    const float* X_true = (const float*)d_in[1];
    const float* R_pred = (const float*)d_in[2];
    const float* t_pred = (const float*)d_in[3];
    const float* R_true = (const float*)d_in[4];
    const float* t_true = (const float*)d_in[5];
    const float* temp   = (const float*)d_in[6];
    float* out = (float*)d_out;

    float4* Pg = (float4*)d_ws;   // MSPL * B*N float4 = 8 MB, fully overwritten

    hipMemsetAsync(out, 0, sizeof(float), stream);

    softfape_main<<<dim3(B_ * 8 * MSPL), BLOCK, 0, stream>>>(
        X_pred, X_true, R_pred, t_pred, R_true, t_true, temp, Pg);

    softfape_finalize<<<dim3((B_ * N_) / 256), 256, 0, stream>>>(Pg, temp, out);
}

// Round 10
// 105.595 us; speedup vs baseline: 1.9996x; 1.9996x over previous
//
#include <hip/hip_runtime.h>

// SoftFAPELoss: B=8, N=M=4096, D=3. Exact two-pass shifted softmax,
// packed-FP32 hot loop, 8 rows/lane, occupancy-tuned.
// softfape_main: grid 1024 x 512 thr (8 waves) = 4 blocks/CU (LDS 40960 B
//   -> exactly 4 blocks fit; VGPR ~40 -> 12 waves/SIMD cap; grid = 4/CU).
//   Block = (b, 512-row group, 1/16th of M = 256 q). q's transformed+
//   prescaled into 4 KB LDS (q.xyz = -2c*y, q.w = c*|y|^2); wave scans a
//   32-q slice via wave-uniform ds_read_b128 broadcast; lane owns 8 rows
//   as 4 float2 packs.
//   Pass 1: A = q.p + c|q|^2 (3 pk_fma), minA = pk_min. Block merge across
//     8 waves -> uniform per-row shift sh (A-units).
//   Pass 2: arg = sh - A <= 0 (pk), w = exp2(arg), L += w, SA += w*arg.
//     Chunk-min term -> w = 1 exactly, so L >= 1: no underflow possible.
//   ONE 16 KB partial buffer reused (minima -> L -> SA) with barriers.
//   NOTE launch_bounds(512,6): (512,8) made the allocator spill the packed
//   accumulators to scratch (R9: 374 MB HBM/dispatch, 3.6x wall). Keep 6.
// softfape_finalize: merge 16 chunk partials per row (exp2(m - m_i) <= 1),
//   wd = m - SA/L, block-reduce, atomicAdd * T*ln2/(B*N).

#define B_    8
#define N_    4096
#define M_    4096
#define NWAVE 8
#define BLOCK (NWAVE * 64)        // 512
#define ROWS  512                 // rows per block (8 per lane)
#define MSPL  16                  // M split across blocks
#define QCH   (M_ / MSPL)         // 256 q per block
#define WQ    (QCH / NWAVE)       // 32 q per wave
#define LOG2E 1.4426950408889634f
#define LN2   0.6931471805599453f
#define BIGF  3.0e38f

typedef float v2f __attribute__((ext_vector_type(2)));

__global__ __launch_bounds__(BLOCK, 6) void softfape_main(
    const float* __restrict__ X_pred, const float* __restrict__ X_true,
    const float* __restrict__ R_pred, const float* __restrict__ t_pred,
    const float* __restrict__ R_true, const float* __restrict__ t_true,
    const float* __restrict__ temp,
    float4* __restrict__ Pg)
{
    __shared__ float4 Q[QCH];            // 4 KB
    __shared__ float  Wp[NWAVE][ROWS];   // 16 KB, reused: minima -> L -> SA
    __shared__ float  shl[ROWS];         // 2 KB (uniform shift per row, A-units)
    __shared__ float  pwl[ROWS];         // 2 KB (c*|p|^2 per row)

    const int tid  = threadIdx.x;
    const int wave = tid >> 6;
    const int lane = tid & 63;
    const int x    = blockIdx.x;
    const int ms   = x & 15;
    const int rg   = (x >> 4) & 7;       // 8 row-groups of 512 rows
    const int b    = x >> 7;

    const float T   = temp[0];
    const float c   = LOG2E / T;
    const float m2c = -2.0f * c;

    // ---- stage 256 transformed+prescaled q's (threads 0..127, 2 each) ----
    if (tid < QCH / 2) {
        const float g00 = R_true[b*9+0], g01 = R_true[b*9+1], g02 = R_true[b*9+2];
        const float g10 = R_true[b*9+3], g11 = R_true[b*9+4], g12 = R_true[b*9+5];
        const float g20 = R_true[b*9+6], g21 = R_true[b*9+7], g22 = R_true[b*9+8];
        const float u0  = t_true[b*3+0], u1 = t_true[b*3+1], u2 = t_true[b*3+2];
        const float2* xt = (const float2*)(X_true + ((size_t)b * M_ + ms * QCH) * 3);
        const float2 f0 = xt[3*tid+0], f1 = xt[3*tid+1], f2 = xt[3*tid+2];
        {
            const float y0 = fmaf(g00, f0.x, fmaf(g01, f0.y, fmaf(g02, f1.x, u0)));
            const float y1 = fmaf(g10, f0.x, fmaf(g11, f0.y, fmaf(g12, f1.x, u1)));
            const float y2 = fmaf(g20, f0.x, fmaf(g21, f0.y, fmaf(g22, f1.x, u2)));
            const float nn = fmaf(y0, y0, fmaf(y1, y1, y2 * y2));
            Q[2*tid]   = make_float4(m2c*y0, m2c*y1, m2c*y2, c*nn);
        }
        {
            const float y0 = fmaf(g00, f1.y, fmaf(g01, f2.x, fmaf(g02, f2.y, u0)));
            const float y1 = fmaf(g10, f1.y, fmaf(g11, f2.x, fmaf(g12, f2.y, u1)));
            const float y2 = fmaf(g20, f1.y, fmaf(g21, f2.x, fmaf(g22, f2.y, u2)));
            const float nn = fmaf(y0, y0, fmaf(y1, y1, y2 * y2));
            Q[2*tid+1] = make_float4(m2c*y0, m2c*y1, m2c*y2, c*nn);
        }
    }

    // ---- my 8 rows: transform, pack into float2 pairs ----
    v2f px2[4], py2[4], pz2[4];
    {
        const float h00 = R_pred[b*9+0], h01 = R_pred[b*9+1], h02 = R_pred[b*9+2];
        const float h10 = R_pred[b*9+3], h11 = R_pred[b*9+4], h12 = R_pred[b*9+5];
        const float h20 = R_pred[b*9+6], h21 = R_pred[b*9+7], h22 = R_pred[b*9+8];
        const float v0 = t_pred[b*3+0], v1 = t_pred[b*3+1], v2 = t_pred[b*3+2];
        const float4* xp = (const float4*)(X_pred + ((size_t)b * N_ + rg * ROWS + lane * 8) * 3);
        const float4 a0 = xp[0], a1 = xp[1], a2 = xp[2];
        const float4 a3 = xp[3], a4 = xp[4], a5 = xp[5];
        const float rx[8] = {a0.x, a0.w, a1.z, a2.y, a3.x, a3.w, a4.z, a5.y};
        const float ry[8] = {a0.y, a1.x, a1.w, a2.z, a3.y, a4.x, a4.w, a5.z};
        const float rz[8] = {a0.z, a1.y, a2.x, a2.w, a3.z, a4.y, a5.x, a5.w};
        #pragma unroll
        for (int j = 0; j < 8; ++j) {
            const float ppx = fmaf(h00, rx[j], fmaf(h01, ry[j], fmaf(h02, rz[j], v0)));
            const float ppy = fmaf(h10, rx[j], fmaf(h11, ry[j], fmaf(h12, rz[j], v1)));
            const float ppz = fmaf(h20, rx[j], fmaf(h21, ry[j], fmaf(h22, rz[j], v2)));
            px2[j >> 1][j & 1] = ppx;
            py2[j >> 1][j & 1] = ppy;
            pz2[j >> 1][j & 1] = ppz;
            if (wave == 0) pwl[8*lane + j] = c * fmaf(ppx, ppx, fmaf(ppy, ppy, ppz * ppz));
        }
    }

    __syncthreads();   // #1: Q, pwl staged

    const float4* __restrict__ Qw = Q + wave * WQ;

    // ---- pass 1: packed min of A over my 32-q slice ----
    v2f mA2[4] = {{BIGF, BIGF}, {BIGF, BIGF}, {BIGF, BIGF}, {BIGF, BIGF}};
    #pragma unroll 4
    for (int k = 0; k < WQ; ++k) {
        const float4 q = Qw[k];   // ds_read_b128, wave-uniform broadcast
        const v2f qx = {q.x, q.x}, qy = {q.y, q.y}, qz = {q.z, q.z}, qw = {q.w, q.w};
        #pragma unroll
        for (int j = 0; j < 4; ++j) {
            const v2f A = qx * px2[j] + (qy * py2[j] + (qz * pz2[j] + qw));
            mA2[j] = __builtin_elementwise_min(mA2[j], A);
        }
    }
    #pragma unroll
    for (int j = 0; j < 4; ++j) {
        Wp[wave][8*lane + 2*j]     = mA2[j].x;
        Wp[wave][8*lane + 2*j + 1] = mA2[j].y;
    }
    __syncthreads();   // #2: minima written

    // ---- block-uniform per-row shift (A-units) ----
    {
        float m = Wp[0][tid];
        #pragma unroll
        for (int w2 = 1; w2 < NWAVE; ++w2) m = fminf(m, Wp[w2][tid]);
        shl[tid] = m;
    }
    __syncthreads();   // #3: shl ready, all Wp reads done

    v2f sh2[4];
    {
        const float4 s0 = *(const float4*)&shl[8*lane];
        const float4 s1 = *(const float4*)&shl[8*lane + 4];
        sh2[0] = (v2f){s0.x, s0.y};  sh2[1] = (v2f){s0.z, s0.w};
        sh2[2] = (v2f){s1.x, s1.y};  sh2[3] = (v2f){s1.z, s1.w};
    }

    // ---- pass 2: packed shifted sums ----
    v2f L2[4]  = {{0.f,0.f},{0.f,0.f},{0.f,0.f},{0.f,0.f}};
    v2f SA2[4] = {{0.f,0.f},{0.f,0.f},{0.f,0.f},{0.f,0.f}};
    #pragma unroll 4
    for (int k = 0; k < WQ; ++k) {
        const float4 q = Qw[k];
        const v2f qx = {q.x, q.x}, qy = {q.y, q.y}, qz = {q.z, q.z}, qw = {q.w, q.w};
        #pragma unroll
        for (int j = 0; j < 4; ++j) {
            const v2f A   = qx * px2[j] + (qy * py2[j] + (qz * pz2[j] + qw));
            const v2f arg = sh2[j] - A;                       // <= 0
            const v2f w   = {__builtin_amdgcn_exp2f(arg.x),
                             __builtin_amdgcn_exp2f(arg.y)};  // chunk-min -> 1
            L2[j]  += w;
            SA2[j]  = w * arg + SA2[j];                       // Sum w*(m_d - d)
        }
    }

    // ---- merge L (reuse Wp), then SA (reuse Wp again) ----
    #pragma unroll
    for (int j = 0; j < 4; ++j) {
        Wp[wave][8*lane + 2*j]     = L2[j].x;
        Wp[wave][8*lane + 2*j + 1] = L2[j].y;
    }
    __syncthreads();   // #4: L partials written
    float Lr = 0.0f;
    #pragma unroll
    for (int w2 = 0; w2 < NWAVE; ++w2) Lr += Wp[w2][tid];
    __syncthreads();   // #5: L reads done
    #pragma unroll
    for (int j = 0; j < 4; ++j) {
        Wp[wave][8*lane + 2*j]     = SA2[j].x;
        Wp[wave][8*lane + 2*j + 1] = SA2[j].y;
    }
    __syncthreads();   // #6: SA partials written
    float Sr = 0.0f;
    #pragma unroll
    for (int w2 = 0; w2 < NWAVE; ++w2) Sr += Wp[w2][tid];

    // ---- chunk partial out (chunk-major, lane-coalesced) ----
    {
        const size_t row = (size_t)b * N_ + rg * ROWS + tid;
        // m_d = minA + pw (d-units); L = sum exp2(m_d - d); SA = sum w*(m_d - d)
        Pg[(size_t)ms * (B_ * N_) + row] = make_float4(shl[tid] + pwl[tid], Lr, Sr, 0.0f);
    }
}

__global__ __launch_bounds__(256) void softfape_finalize(
    const float4* __restrict__ Pg, const float* __restrict__ temp,
    float* __restrict__ out)
{
    __shared__ float ws4[4];
    const int tid = threadIdx.x;
    const size_t row = (size_t)blockIdx.x * 256 + tid;

    float4 P[MSPL];
    #pragma unroll
    for (int i = 0; i < MSPL; ++i) P[i] = Pg[(size_t)i * (B_ * N_) + row];

    float m = P[0].x;
    #pragma unroll
    for (int i = 1; i < MSPL; ++i) m = fminf(m, P[i].x);

    float L = 0.0f, SA = 0.0f;
    #pragma unroll
    for (int i = 0; i < MSPL; ++i) {
        const float dm = m - P[i].x;                    // <= 0
        const float f  = __builtin_amdgcn_exp2f(dm);    // global-min chunk -> 1
        L  = fmaf(P[i].y, f, L);
        SA = fmaf(f, fmaf(dm, P[i].y, P[i].z), SA);
    }
    float wd = m - SA / L;   // = c * weighted_distance(row); L >= 1 guaranteed

    wd += __shfl_xor(wd, 1);  wd += __shfl_xor(wd, 2);  wd += __shfl_xor(wd, 4);
    wd += __shfl_xor(wd, 8);  wd += __shfl_xor(wd, 16); wd += __shfl_xor(wd, 32);
    if ((tid & 63) == 0) ws4[tid >> 6] = wd;
    __syncthreads();
    if (tid == 0) {
        const float s = ws4[0] + ws4[1] + ws4[2] + ws4[3];
        const float scale = temp[0] * LN2 / ((float)B_ * (float)N_);  // 1/c, mean
        atomicAdd(out, s * scale);
    }
}

extern "C" void kernel_launch(void* const* d_in, const int* in_sizes, int n_in,
                              void* d_out, int out_size, void* d_ws, size_t ws_size,
                              hipStream_t stream) {
    const float* X_pred = (const float*)d_in[0];
    const float* X_true = (const float*)d_in[1];
    const float* R_pred = (const float*)d_in[2];
    const float* t_pred = (const float*)d_in[3];
    const float* R_true = (const float*)d_in[4];
    const float* t_true = (const float*)d_in[5];
    const float* temp   = (const float*)d_in[6];
    float* out = (float*)d_out;

    float4* Pg = (float4*)d_ws;   // MSPL * B*N float4 = 8 MB, fully overwritten

    hipMemsetAsync(out, 0, sizeof(float), stream);

    softfape_main<<<dim3(B_ * 8 * MSPL), BLOCK, 0, stream>>>(
        X_pred, X_true, R_pred, t_pred, R_true, t_true, temp, Pg);

    softfape_finalize<<<dim3((B_ * N_) / 256), 256, 0, stream>>>(Pg, temp, out);
}

// Round 11
// 104.363 us; speedup vs baseline: 2.0232x; 1.0118x over previous
//
#include <hip/hip_runtime.h>

// SoftFAPELoss: B=8, N=M=4096, D=3. Exact two-pass shifted softmax.
// R11: fp16-packed pass-1 (v_pk_fma_f16/v_pk_min_f16; shift only needs to be
// within ~100 c-units of true min -> fp16 error ~0.2 is 400x inside margin),
// wave-local shift so BOTH hot loops run barrier-free, post-loop rescale
// (delta = global_row_min - own_min <= 0: L*=2^d, SA=2^d*(SA+d*L)) re-aligns
// the 8 wave partials to a common per-row shift before plain-add merges.
// Grid 1024 x 512 thr (8 waves) = 4 blocks/CU; LDS 28 KB; VGPR ~40-60.
// NOTE launch_bounds(512,6): (512,8) spilled accumulators (R9). Keep 6.
// NOTE no v_pk_*_f32 path: CDNA4 scalar fp32 runs at the full 157 TF rate
// (m07), so packed fp32 cannot beat scalar issue; fp16 packed is 2x.

#define B_    8
#define N_    4096
#define M_    4096
#define NWAVE 8
#define BLOCK (NWAVE * 64)        // 512
#define ROWS  512                 // rows per block (8 per lane)
#define MSPL  16                  // M split across blocks
#define QCH   (M_ / MSPL)         // 256 q per block
#define WQ    (QCH / NWAVE)       // 32 q per wave
#define LOG2E 1.4426950408889634f
#define LN2   0.6931471805599453f
#define BIGF  3.0e38f

typedef float    v2f __attribute__((ext_vector_type(2)));
typedef _Float16 h2  __attribute__((ext_vector_type(2)));

__global__ __launch_bounds__(BLOCK, 6) void softfape_main(
    const float* __restrict__ X_pred, const float* __restrict__ X_true,
    const float* __restrict__ R_pred, const float* __restrict__ t_pred,
    const float* __restrict__ R_true, const float* __restrict__ t_true,
    const float* __restrict__ temp,
    float4* __restrict__ Pg)
{
    __shared__ uint4  Qh[QCH];           // 4 KB: q duplicated as half2 x4
    __shared__ float4 Q[QCH];            // 4 KB: fp32 q for pass 2
    __shared__ float  Wp[NWAVE][ROWS];   // 16 KB, reused: minima -> L -> SA
    __shared__ float  shl[ROWS];         // 2 KB (global per-row shift, A-units)
    __shared__ float  pwl[ROWS];         // 2 KB (c*|p|^2 per row)

    const int tid  = threadIdx.x;
    const int wave = tid >> 6;
    const int lane = tid & 63;
    const int x    = blockIdx.x;
    const int ms   = x & 15;
    const int rg   = (x >> 4) & 7;       // 8 row-groups of 512 rows
    const int b    = x >> 7;

    const float T   = temp[0];
    const float c   = LOG2E / T;
    const float m2c = -2.0f * c;

    // ---- stage 256 q's: fp32 (Q) + duplicated-half2 (Qh). 128 thr, 2 each ----
    if (tid < QCH / 2) {
        const float g00 = R_true[b*9+0], g01 = R_true[b*9+1], g02 = R_true[b*9+2];
        const float g10 = R_true[b*9+3], g11 = R_true[b*9+4], g12 = R_true[b*9+5];
        const float g20 = R_true[b*9+6], g21 = R_true[b*9+7], g22 = R_true[b*9+8];
        const float u0  = t_true[b*3+0], u1 = t_true[b*3+1], u2 = t_true[b*3+2];
        const float2* xt = (const float2*)(X_true + ((size_t)b * M_ + ms * QCH) * 3);
        const float2 f0 = xt[3*tid+0], f1 = xt[3*tid+1], f2 = xt[3*tid+2];
        #pragma unroll
        for (int e = 0; e < 2; ++e) {
            const float xx = e ? f1.y : f0.x;
            const float yy = e ? f2.x : f0.y;
            const float zz = e ? f2.y : f1.x;
            const float y0 = fmaf(g00, xx, fmaf(g01, yy, fmaf(g02, zz, u0)));
            const float y1 = fmaf(g10, xx, fmaf(g11, yy, fmaf(g12, zz, u1)));
            const float y2 = fmaf(g20, xx, fmaf(g21, yy, fmaf(g22, zz, u2)));
            const float nn = fmaf(y0, y0, fmaf(y1, y1, y2 * y2));
            const float qx = m2c * y0, qy = m2c * y1, qz = m2c * y2, qw = c * nn;
            Q[2*tid + e] = make_float4(qx, qy, qz, qw);
            const h2 hx = {(_Float16)qx, (_Float16)qx};
            const h2 hy = {(_Float16)qy, (_Float16)qy};
            const h2 hz = {(_Float16)qz, (_Float16)qz};
            const h2 hw = {(_Float16)qw, (_Float16)qw};
            uint4 u;
            u.x = __builtin_bit_cast(unsigned, hx);
            u.y = __builtin_bit_cast(unsigned, hy);
            u.z = __builtin_bit_cast(unsigned, hz);
            u.w = __builtin_bit_cast(unsigned, hw);
            Qh[2*tid + e] = u;
        }
    }

    // ---- my 8 rows: transform, fp32 packs + fp16 packs ----
    v2f px2[4], py2[4], pz2[4];
    h2  hpx[4], hpy[4], hpz[4];
    {
        const float h00 = R_pred[b*9+0], h01 = R_pred[b*9+1], h02 = R_pred[b*9+2];
        const float h10 = R_pred[b*9+3], h11 = R_pred[b*9+4], h12 = R_pred[b*9+5];
        const float h20 = R_pred[b*9+6], h21 = R_pred[b*9+7], h22 = R_pred[b*9+8];
        const float v0 = t_pred[b*3+0], v1 = t_pred[b*3+1], v2 = t_pred[b*3+2];
        const float4* xp = (const float4*)(X_pred + ((size_t)b * N_ + rg * ROWS + lane * 8) * 3);
        const float4 a0 = xp[0], a1 = xp[1], a2 = xp[2];
        const float4 a3 = xp[3], a4 = xp[4], a5 = xp[5];
        const float rx[8] = {a0.x, a0.w, a1.z, a2.y, a3.x, a3.w, a4.z, a5.y};
        const float ry[8] = {a0.y, a1.x, a1.w, a2.z, a3.y, a4.x, a4.w, a5.z};
        const float rz[8] = {a0.z, a1.y, a2.x, a2.w, a3.z, a4.y, a5.x, a5.w};
        #pragma unroll
        for (int j = 0; j < 8; ++j) {
            const float ppx = fmaf(h00, rx[j], fmaf(h01, ry[j], fmaf(h02, rz[j], v0)));
            const float ppy = fmaf(h10, rx[j], fmaf(h11, ry[j], fmaf(h12, rz[j], v1)));
            const float ppz = fmaf(h20, rx[j], fmaf(h21, ry[j], fmaf(h22, rz[j], v2)));
            px2[j >> 1][j & 1] = ppx;
            py2[j >> 1][j & 1] = ppy;
            pz2[j >> 1][j & 1] = ppz;
            hpx[j >> 1][j & 1] = (_Float16)ppx;
            hpy[j >> 1][j & 1] = (_Float16)ppy;
            hpz[j >> 1][j & 1] = (_Float16)ppz;
            if (wave == 0) pwl[8*lane + j] = c * fmaf(ppx, ppx, fmaf(ppy, ppy, ppz * ppz));
        }
    }

    __syncthreads();   // #1: Q, Qh, pwl staged

    const uint4*  __restrict__ Qhw = Qh + wave * WQ;
    const float4* __restrict__ Qw  = Q  + wave * WQ;

    // ---- pass 1 (fp16 packed, barrier-free): min of A over my 32-q slice ----
    h2 mH[4];
    #pragma unroll
    for (int j = 0; j < 4; ++j) mH[j] = (h2){(_Float16)30000.0f, (_Float16)30000.0f};
    #pragma unroll 4
    for (int k = 0; k < WQ; ++k) {
        const uint4 qq = Qhw[k];   // ds_read_b128, wave-uniform broadcast
        const h2 hqx = __builtin_bit_cast(h2, qq.x);
        const h2 hqy = __builtin_bit_cast(h2, qq.y);
        const h2 hqz = __builtin_bit_cast(h2, qq.z);
        const h2 hqw = __builtin_bit_cast(h2, qq.w);
        #pragma unroll
        for (int j = 0; j < 4; ++j) {
            const h2 Ah = __builtin_elementwise_fma(hqx, hpx[j],
                          __builtin_elementwise_fma(hqy, hpy[j],
                          __builtin_elementwise_fma(hqz, hpz[j], hqw)));
            mH[j] = __builtin_elementwise_min(mH[j], Ah);
        }
    }
    // wave-local shift (A-units), fp32
    v2f sh2[4];
    #pragma unroll
    for (int j = 0; j < 4; ++j) sh2[j] = (v2f){(float)mH[j].x, (float)mH[j].y};

    // ---- pass 2 (fp32, barrier-free): shifted sums with OWN wave shift ----
    v2f L2[4]  = {{0.f,0.f},{0.f,0.f},{0.f,0.f},{0.f,0.f}};
    v2f SA2[4] = {{0.f,0.f},{0.f,0.f},{0.f,0.f},{0.f,0.f}};
    #pragma unroll 4
    for (int k = 0; k < WQ; ++k) {
        const float4 q = Qw[k];
        const v2f qx = {q.x, q.x}, qy = {q.y, q.y}, qz = {q.z, q.z}, qw = {q.w, q.w};
        #pragma unroll
        for (int j = 0; j < 4; ++j) {
            const v2f A   = qx * px2[j] + (qy * py2[j] + (qz * pz2[j] + qw));
            const v2f arg = sh2[j] - A;                       // <= ~ +0.2 (fp16 slack)
            const v2f w   = {__builtin_amdgcn_exp2f(arg.x),
                             __builtin_amdgcn_exp2f(arg.y)};  // <= ~1.15, no overflow
            L2[j]  += w;
            SA2[j]  = w * arg + SA2[j];                       // Sum w*(sh - A)
        }
    }

    // ---- merge: own minima -> global per-row shift ----
    #pragma unroll
    for (int j = 0; j < 4; ++j) {
        Wp[wave][8*lane + 2*j]     = sh2[j].x;
        Wp[wave][8*lane + 2*j + 1] = sh2[j].y;
    }
    __syncthreads();   // #2: minima written
    {
        float m = Wp[0][tid];
        #pragma unroll
        for (int w2 = 1; w2 < NWAVE; ++w2) m = fminf(m, Wp[w2][tid]);
        shl[tid] = m;
    }
    __syncthreads();   // #3: shl ready, Wp reads done

    // ---- rescale own partials to the global shift: d = shl - own <= 0 ----
    {
        const float4 s0 = *(const float4*)&shl[8*lane];
        const float4 s1 = *(const float4*)&shl[8*lane + 4];
        const v2f g2[4] = {{s0.x, s0.y}, {s0.z, s0.w}, {s1.x, s1.y}, {s1.z, s1.w}};
        #pragma unroll
        for (int j = 0; j < 4; ++j) {
            const v2f dl = g2[j] - sh2[j];                    // <= 0 exactly
            const v2f f  = {__builtin_amdgcn_exp2f(dl.x), __builtin_amdgcn_exp2f(dl.y)};
            SA2[j] = f * (SA2[j] + dl * L2[j]);
            L2[j]  = f * L2[j];
        }
    }

    // ---- merge L (reuse Wp), then SA (reuse Wp) ----
    #pragma unroll
    for (int j = 0; j < 4; ++j) {
        Wp[wave][8*lane + 2*j]     = L2[j].x;
        Wp[wave][8*lane + 2*j + 1] = L2[j].y;
    }
    __syncthreads();   // #4: L partials written
    float Lr = 0.0f;
    #pragma unroll
    for (int w2 = 0; w2 < NWAVE; ++w2) Lr += Wp[w2][tid];
    __syncthreads();   // #5: L reads done
    #pragma unroll
    for (int j = 0; j < 4; ++j) {
        Wp[wave][8*lane + 2*j]     = SA2[j].x;
        Wp[wave][8*lane + 2*j + 1] = SA2[j].y;
    }
    __syncthreads();   // #6: SA partials written
    float Sr = 0.0f;
    #pragma unroll
    for (int w2 = 0; w2 < NWAVE; ++w2) Sr += Wp[w2][tid];

    // ---- chunk partial out (chunk-major, lane-coalesced) ----
    {
        const size_t row = (size_t)b * N_ + rg * ROWS + tid;
        // m_d = sh + pw (d-units); L = sum exp2(sh - A); SA = sum w*(sh - A)
        Pg[(size_t)ms * (B_ * N_) + row] = make_float4(shl[tid] + pwl[tid], Lr, Sr, 0.0f);
    }
}

__global__ __launch_bounds__(256) void softfape_finalize(
    const float4* __restrict__ Pg, const float* __restrict__ temp,
    float* __restrict__ out)
{
    __shared__ float ws4[4];
    const int tid = threadIdx.x;
    const size_t row = (size_t)blockIdx.x * 256 + tid;

    float4 P[MSPL];
    #pragma unroll
    for (int i = 0; i < MSPL; ++i) P[i] = Pg[(size_t)i * (B_ * N_) + row];

    float m = P[0].x;
    #pragma unroll
    for (int i = 1; i < MSPL; ++i) m = fminf(m, P[i].x);

    float L = 0.0f, SA = 0.0f;
    #pragma unroll
    for (int i = 0; i < MSPL; ++i) {
        const float dm = m - P[i].x;                    // <= 0
        const float f  = __builtin_amdgcn_exp2f(dm);
        L  = fmaf(P[i].y, f, L);
        SA = fmaf(f, fmaf(dm, P[i].y, P[i].z), SA);
    }
    float wd = m - SA / L;   // = c * weighted_distance(row); L >= ~0.87 guaranteed

    wd += __shfl_xor(wd, 1);  wd += __shfl_xor(wd, 2);  wd += __shfl_xor(wd, 4);
    wd += __shfl_xor(wd, 8);  wd += __shfl_xor(wd, 16); wd += __shfl_xor(wd, 32);
    if ((tid & 63) == 0) ws4[tid >> 6] = wd;
    __syncthreads();
    if (tid == 0) {
        const float s = ws4[0] + ws4[1] + ws4[2] + ws4[3];
        const float scale = temp[0] * LN2 / ((float)B_ * (float)N_);  // 1/c, mean
        atomicAdd(out, s * scale);
    }
}

extern "C" void kernel_launch(void* const* d_in, const int* in_sizes, int n_in,
                              void* d_out, int out_size, void* d_ws, size_t ws_size,
                              hipStream_t stream) {
    const float* X_pred = (const float*)d_in[0];
    const float* X_true = (const float*)d_in[1];
    const float* R_pred = (const float*)d_in[2];
    const float* t_pred = (const float*)d_in[3];
    const float* R_true = (const float*)d_in[4];
    const float* t_true = (const float*)d_in[5];
    const float* temp   = (const float*)d_in[6];
    float* out = (float*)d_out;

    float4* Pg = (float4*)d_ws;   // MSPL * B*N float4 = 8 MB, fully overwritten

    hipMemsetAsync(out, 0, sizeof(float), stream);

    softfape_main<<<dim3(B_ * 8 * MSPL), BLOCK, 0, stream>>>(
        X_pred, X_true, R_pred, t_pred, R_true, t_true, temp, Pg);

    softfape_finalize<<<dim3((B_ * N_) / 256), 256, 0, stream>>>(Pg, temp, out);
}